// Round 3
// baseline (2675.774 us; speedup 1.0000x reference)
//
#include <hip/hip_runtime.h>

#define NB 8
#define NC 128
#define FH 96
#define DS 48
#define NP 2304                 // 48*48 patches / locations
#define PP 5308416LL            // NP*NP (per batch)
#define NR 49
#define RR 2401                 // 49*49
#define RRP 2432                // padded attn4 col count (38*64)
#define A4B 5839232LL           // RR*RRP per batch

// ---------- K1a: downsample f,b by 2 (all batches) ----------
extern "C" __global__ void k_prep(const float* __restrict__ f, const float* __restrict__ b,
                                  float* __restrict__ fds, float* __restrict__ bds) {
    int idx = blockIdx.x * 256 + threadIdx.x;
    if (idx >= NB * NC * DS * DS) return;
    int x = idx % DS; int r = idx / DS; int y = r % DS; int bc = r / DS;
    size_t src = ((size_t)bc * FH + 2 * y) * FH + 2 * x;
    fds[idx] = f[src];
    bds[idx] = b[src];
}

// ---------- K1b: S2[b,y,x] = sum_c b_ds^2 (all batches) ----------
extern "C" __global__ void k_s2(const float* __restrict__ bds, float* __restrict__ s2) {
    int idx = blockIdx.x * 256 + threadIdx.x;
    if (idx >= NB * DS * DS) return;
    int sp = idx % (DS * DS); int bb = idx / (DS * DS);
    const float* p = bds + (size_t)bb * NC * DS * DS + sp;
    float acc = 0.f;
    for (int c = 0; c < NC; ++c) { float v = p[(size_t)c * DS * DS]; acc += v * v; }
    s2[idx] = acc;
}

// ---------- K1c: norm[b,p] = sqrt(9-tap box(S2) + 1152e-4), mm[p] (all batches) ----------
extern "C" __global__ void k_norm(const float* __restrict__ s2, const float* __restrict__ mask,
                                  float* __restrict__ normv, float* __restrict__ mmv) {
    int idx = blockIdx.x * 256 + threadIdx.x;
    if (idx >= NB * NP) return;
    int p = idx % NP; int bb = idx / NP;
    int py = p / DS, px = p % DS;
    const float* s2b = s2 + bb * DS * DS;
    float acc = 0.f;
    for (int dy = -1; dy <= 1; ++dy) {
        int yy = py + dy; if ((unsigned)yy >= DS) continue;
        for (int dx = -1; dx <= 1; ++dx) {
            int xx = px + dx; if ((unsigned)xx >= DS) continue;
            acc += s2b[yy * DS + xx];
        }
    }
    normv[idx] = sqrtf(acc + 1152.0f * 1e-4f);
    if (bb == 0) {
        float msum = 0.f;
        for (int dy = -1; dy <= 1; ++dy) {
            int yy = py + dy; if ((unsigned)yy >= DS) continue;
            for (int dx = -1; dx <= 1; ++dx) {
                int xx = px + dx; if ((unsigned)xx >= DS) continue;
                msum += mask[(size_t)(2 * yy) * FH + 2 * xx];
            }
        }
        mmv[p] = (msum == 0.0f) ? 1.0f : 0.0f;
    }
}

// ---------- K2 (per batch): G[p][l] = sum_c b_ds[c,p] * f_ds[c,l] ----------
extern "C" __global__ __launch_bounds__(256) void k_ggemm(const float* __restrict__ bp,
                                                          const float* __restrict__ fp,
                                                          float* __restrict__ G) {
    int p0 = blockIdx.x * 64, l0 = blockIdx.y * 64;
    __shared__ float As[16][64];
    __shared__ float Bs[16][64];
    int tid = threadIdx.x;
    int tx = tid & 15, ty = tid >> 4;
    float acc[4][4] = {};
    int i0 = tid * 4, kk = i0 >> 6, pp = i0 & 63;
    for (int k0 = 0; k0 < NC; k0 += 16) {
        *(float4*)&As[kk][pp] = *(const float4*)(bp + (size_t)(k0 + kk) * NP + p0 + pp);
        *(float4*)&Bs[kk][pp] = *(const float4*)(fp + (size_t)(k0 + kk) * NP + l0 + pp);
        __syncthreads();
#pragma unroll
        for (int k = 0; k < 16; ++k) {
            float av[4], bv[4];
            *(float4*)av = *(float4*)&As[k][ty * 4];
            *(float4*)bv = *(float4*)&Bs[k][tx * 4];
#pragma unroll
            for (int i = 0; i < 4; ++i)
#pragma unroll
                for (int j = 0; j < 4; ++j) acc[i][j] += av[i] * bv[j];
        }
        __syncthreads();
    }
#pragma unroll
    for (int i = 0; i < 4; ++i) {
        float4 v = make_float4(acc[i][0], acc[i][1], acc[i][2], acc[i][3]);
        *(float4*)(G + (size_t)(p0 + ty * 4 + i) * NP + l0 + tx * 4) = v;
    }
}

// ---------- K3 (per batch): scores[p,l] = (sum_d G[p+d,l+d]) / norm[p] ----------
extern "C" __global__ void k_scores(const float* __restrict__ G, const float* __restrict__ normv,
                                    float* __restrict__ sc) {
    long long idx = (long long)blockIdx.x * 256 + threadIdx.x;   // exact: PP
    int l = (int)(idx % NP);
    int p = (int)(idx / NP);
    int py = p / DS, px = p % DS, ly = l / DS, lx = l % DS;
    float acc = 0.f;
#pragma unroll
    for (int dy = -1; dy <= 1; ++dy) {
        int pyy = py + dy, lyy = ly + dy;
        if ((unsigned)pyy >= DS || (unsigned)lyy >= DS) continue;
#pragma unroll
        for (int dx = -1; dx <= 1; ++dx) {
            int pxx = px + dx, lxx = lx + dx;
            if ((unsigned)pxx >= DS || (unsigned)lxx >= DS) continue;
            acc += G[(size_t)(pyy * DS + pxx) * NP + (lyy * DS + lxx)];
        }
    }
    sc[idx] = acc / normv[p];
}

// ---------- K4 (per batch): both fuse_diag passes ----------
extern "C" __global__ void k_fuse(const float* __restrict__ sc, float* __restrict__ sf) {
    long long idx = (long long)blockIdx.x * 256 + threadIdx.x;   // exact: PP
    int l = (int)(idx % NP);
    int p = (int)(idx / NP);
    int hb = p / DS, wb = p % DS, hf = l / DS, wf = l % DS;
    float acc = 0.f;
#pragma unroll
    for (int e2 = -1; e2 <= 1; ++e2) {
        int qp = wb * DS + hb + e2;
        int ql = wf * DS + hf + e2;
        if ((unsigned)qp >= NP || (unsigned)ql >= NP) continue;
        int wb2 = qp / DS, hb2 = qp % DS, wf2 = ql / DS, hf2 = ql % DS;
        int P1 = hb2 * DS + wb2, L1 = hf2 * DS + wf2;
#pragma unroll
        for (int e1 = -1; e1 <= 1; ++e1) {
            int Pz = P1 + e1, Lz = L1 + e1;
            if ((unsigned)Pz >= NP || (unsigned)Lz >= NP) continue;
            acc += sc[(size_t)Pz * NP + Lz];
        }
    }
    sf[idx] = acc;
}

// ---------- K5a (per batch): per-column online softmax partials over p-chunks ----------
extern "C" __global__ void k_stats1(const float* __restrict__ sf, const float* __restrict__ mmv,
                                    float* __restrict__ pM, float* __restrict__ pS) {
    int l = blockIdx.x * 256 + threadIdx.x;   // exactly covers [0,2304)
    int pst = blockIdx.y * 128;
    const float* base = sf + (size_t)pst * NP + l;
    float m = -1e30f, s = 0.f;
    for (int i = 0; i < 128; ++i) {
        float x = (mmv[pst + i] != 0.0f) ? 10.0f * base[(size_t)i * NP] : 0.0f;
        float mn = fmaxf(m, x);
        s = s * __expf(m - mn) + __expf(x - mn);
        m = mn;
    }
    int o = blockIdx.y * NP + l;
    pM[o] = m; pS[o] = s;
}

// ---------- K5b (per batch): combine partials -> M, 1/S ----------
extern "C" __global__ void k_stats2(const float* __restrict__ pM, const float* __restrict__ pS,
                                    float* __restrict__ M, float* __restrict__ Sinv) {
    int l = blockIdx.x * 256 + threadIdx.x;   // exactly covers [0,2304)
    float m = -1e30f, s = 0.f;
    for (int j = 0; j < 18; ++j) {
        int o = j * NP + l;
        float mj = pM[o], sj = pS[o];
        float mn = fmaxf(m, mj);
        s = s * __expf(m - mn) + sj * __expf(mj - mn);
        m = mn;
    }
    M[l] = m;
    Sinv[l] = 1.0f / s;
}

// ---------- K6 (per batch): attn4[r, mt] = sum_{d in {0,1}^2} attn[r-d, mt-d] ----------
extern "C" __global__ void k_attn4(const float* __restrict__ sf, const float* __restrict__ mmv,
                                   const float* __restrict__ M, const float* __restrict__ Sinv,
                                   float* __restrict__ a4) {
    long long idx = (long long)blockIdx.x * 256 + threadIdx.x;
    if (idx >= (long long)RR * RRP) return;
    int mt = (int)(idx % RRP);
    int r = (int)(idx / RRP);
    int ry = r / NR, rx = r % NR, my = mt / NR, mx = mt % NR;
    float acc = 0.f;
#pragma unroll
    for (int dy = 0; dy <= 1; ++dy) {
        int py = ry - dy, ly = my - dy;
        if ((unsigned)py >= DS || (unsigned)ly >= DS) continue;
#pragma unroll
        for (int dx = 0; dx <= 1; ++dx) {
            int px = rx - dx, lx = mx - dx;
            if ((unsigned)px >= DS || (unsigned)lx >= DS) continue;
            int p = py * DS + px, l = ly * DS + lx;
            if (mmv[p] != 0.0f)
                acc += __expf(10.0f * sf[(size_t)p * NP + l] - M[l]) * Sinv[l];
        }
    }
    a4[idx] = acc;
}

// ---------- K7 (per batch PAIR): out[c,2m+a] = 0.25 * sum_r b[c,2r-a]*attn4[r,m+a] ----------
extern "C" __global__ __launch_bounds__(256) void k_deconv(const float* __restrict__ a4pair,
                                                           const float* __restrict__ bfull,
                                                           float* __restrict__ out, int bb0) {
    int jb = blockIdx.z >> 2;           // 0..1 within pair
    int par = blockIdx.z & 3;
    int bb = bb0 + jb;
    int ay = par >> 1, ax = par & 1;
    int m0 = blockIdx.x * 64;
    int c0 = blockIdx.y * 64;
    __shared__ float As[16][64];
    __shared__ float Bs[16][68];
    int tid = threadIdx.x;
    int tx = tid & 15, ty = tid >> 4;
    const float* a4b = a4pair + (size_t)jb * A4B;
    const float* bbase = bfull + (size_t)bb * NC * FH * FH;
    float acc[4][4] = {};
    int i0 = tid * 4, kk = i0 >> 6, ml = i0 & 63;
    int bk = tid & 15;
    int bc = (tid >> 4) * 4;
    for (int r0 = 0; r0 < RR; r0 += 16) {
        int rr = r0 + kk;
        float4 va = make_float4(0.f, 0.f, 0.f, 0.f);
        if (rr < RR) va = *(const float4*)(a4b + (size_t)rr * RRP + m0 + ml);
        *(float4*)&As[kk][ml] = va;

        int rb = r0 + bk;
        int ry = rb / NR, rx = rb % NR;
        int by = 2 * ry - ay;
        int bx = 2 * rx - ax;
        bool vb = (rb < RR) && ((unsigned)by < FH) && ((unsigned)bx < FH);
#pragma unroll
        for (int i = 0; i < 4; ++i) {
            float v = 0.f;
            if (vb) v = bbase[((size_t)(c0 + bc + i) * FH + by) * FH + bx];
            Bs[bk][bc + i] = v;
        }
        __syncthreads();
#pragma unroll
        for (int k = 0; k < 16; ++k) {
            float av[4], bv[4];
            *(float4*)av = *(float4*)&As[k][tx * 4];
            bv[0] = Bs[k][ty * 4]; bv[1] = Bs[k][ty * 4 + 1];
            bv[2] = Bs[k][ty * 4 + 2]; bv[3] = Bs[k][ty * 4 + 3];
#pragma unroll
            for (int i = 0; i < 4; ++i)
#pragma unroll
                for (int j = 0; j < 4; ++j) acc[i][j] += bv[i] * av[j];   // i->c, j->m~
        }
        __syncthreads();
    }
#pragma unroll
    for (int i = 0; i < 4; ++i) {
        int c = c0 + ty * 4 + i;
#pragma unroll
        for (int j = 0; j < 4; ++j) {
            int mt = m0 + tx * 4 + j;
            int my = mt / NR, mx = mt % NR;
            int oy = my - ay, ox = mx - ax;
            if ((unsigned)oy < DS && (unsigned)ox < DS) {
                int y = 2 * oy + ay, x = 2 * ox + ax;
                out[((size_t)(bb * NC + c) * FH + y) * FH + x] = 0.25f * acc[i][j];
            }
        }
    }
}

extern "C" void kernel_launch(void* const* d_in, const int* in_sizes, int n_in,
                              void* d_out, int out_size, void* d_ws, size_t ws_size,
                              hipStream_t stream) {
    const float* f = (const float*)d_in[0];
    const float* b = (const float*)d_in[1];
    const float* mask = (const float*)d_in[2];
    float* out = (float*)d_out;
    float* ws = (float*)d_ws;

    size_t o = 0;
    float* fds = ws + o;   o += (size_t)NB * NC * NP;   // 2,359,296
    float* bds = ws + o;   o += (size_t)NB * NC * NP;   // 2,359,296
    float* s2 = ws + o;    o += NB * DS * DS;           // 18,432
    float* normv = ws + o; o += NB * NP;                // 18,432
    float* mmv = ws + o;   o += NP;                     // 2,304
    float* Mst = ws + o;   o += NB * NP;                // 18,432
    float* Sinv = ws + o;  o += NB * NP;                // 18,432
    float* pM = ws + o;    o += (size_t)18 * NP;        // 41,472
    float* pS = ws + o;    o += (size_t)18 * NP;        // 41,472
    float* X = ws + o;     o += (size_t)PP;             // 5,308,416  (G_b, then sf_b)
    float* Y = ws + o;     o += (size_t)PP;             // 5,308,416  (scores_b)
    float* Z = ws + o;     o += (size_t)2 * A4B;        // 11,678,464 (attn4 pair)
    // total = 27,172,864 floats = 108.7 MB

    if (ws_size < o * sizeof(float)) return;   // diagnostic: clean fail instead of OOB fault

    hipLaunchKernelGGL(k_prep, dim3(9216), dim3(256), 0, stream, f, b, fds, bds);
    hipLaunchKernelGGL(k_s2,   dim3(72),   dim3(256), 0, stream, bds, s2);
    hipLaunchKernelGGL(k_norm, dim3(72),   dim3(256), 0, stream, s2, mask, normv, mmv);

    for (int pair = 0; pair < 4; ++pair) {
        for (int j = 0; j < 2; ++j) {
            int bb = pair * 2 + j;
            const float* bp = bds + (size_t)bb * NC * NP;
            const float* fp = fds + (size_t)bb * NC * NP;
            hipLaunchKernelGGL(k_ggemm,  dim3(36, 36), dim3(256), 0, stream, bp, fp, X);
            hipLaunchKernelGGL(k_scores, dim3(20736),  dim3(256), 0, stream, X, normv + (size_t)bb * NP, Y);
            hipLaunchKernelGGL(k_fuse,   dim3(20736),  dim3(256), 0, stream, Y, X);
            hipLaunchKernelGGL(k_stats1, dim3(9, 18),  dim3(256), 0, stream, X, mmv, pM, pS);
            hipLaunchKernelGGL(k_stats2, dim3(9),      dim3(256), 0, stream, pM, pS,
                               Mst + (size_t)bb * NP, Sinv + (size_t)bb * NP);
            hipLaunchKernelGGL(k_attn4,  dim3(22810),  dim3(256), 0, stream, X, mmv,
                               Mst + (size_t)bb * NP, Sinv + (size_t)bb * NP, Z + (size_t)j * A4B);
        }
        hipLaunchKernelGGL(k_deconv, dim3(38, 2, 8), dim3(256), 0, stream, Z, b, out, pair * 2);
    }
}

// Round 5
// 2491.580 us; speedup vs baseline: 1.0739x; 1.0739x over previous
//
#include <hip/hip_runtime.h>

#define NB 8
#define NC 128
#define FH 96
#define DS 48
#define NP 2304                 // 48*48 patches / locations
#define PP 5308416LL            // NP*NP (per batch)
#define NR 49
#define RR 2401                 // 49*49
#define RRP 2432                // padded attn4 col count (19*128)
#define A4B 5839232LL           // RR*RRP per batch
#define WPB 2490368             // 2*4*NC*RRP  (pair Wpar floats)  = 9728 blocks
#define DBB 2490368             // 2*4*NC*RRP  (pair deconv accum floats)

struct F4u { float a, b, c, d; };   // 4-byte-aligned 4-float load (unaligned dwordx4 ok)

// ---------- K1a: downsample f,b by 2 (all batches) ----------
extern "C" __global__ void k_prep(const float* __restrict__ f, const float* __restrict__ b,
                                  float* __restrict__ fds, float* __restrict__ bds) {
    int idx = blockIdx.x * 256 + threadIdx.x;
    if (idx >= NB * NC * DS * DS) return;
    int x = idx % DS; int r = idx / DS; int y = r % DS; int bc = r / DS;
    size_t src = ((size_t)bc * FH + 2 * y) * FH + 2 * x;
    fds[idx] = f[src];
    bds[idx] = b[src];
}

// ---------- K1b: S2[b,y,x] = sum_c b_ds^2 ----------
extern "C" __global__ void k_s2(const float* __restrict__ bds, float* __restrict__ s2) {
    int idx = blockIdx.x * 256 + threadIdx.x;
    if (idx >= NB * DS * DS) return;
    int sp = idx % (DS * DS); int bb = idx / (DS * DS);
    const float* p = bds + (size_t)bb * NC * DS * DS + sp;
    float acc = 0.f;
    for (int c = 0; c < NC; ++c) { float v = p[(size_t)c * DS * DS]; acc += v * v; }
    s2[idx] = acc;
}

// ---------- K1c: norm, mm ----------
extern "C" __global__ void k_norm(const float* __restrict__ s2, const float* __restrict__ mask,
                                  float* __restrict__ normv, float* __restrict__ mmv) {
    int idx = blockIdx.x * 256 + threadIdx.x;
    if (idx >= NB * NP) return;
    int p = idx % NP; int bb = idx / NP;
    int py = p / DS, px = p % DS;
    const float* s2b = s2 + bb * DS * DS;
    float acc = 0.f;
    for (int dy = -1; dy <= 1; ++dy) {
        int yy = py + dy; if ((unsigned)yy >= DS) continue;
        for (int dx = -1; dx <= 1; ++dx) {
            int xx = px + dx; if ((unsigned)xx >= DS) continue;
            acc += s2b[yy * DS + xx];
        }
    }
    normv[idx] = sqrtf(acc + 1152.0f * 1e-4f);
    if (bb == 0) {
        float msum = 0.f;
        for (int dy = -1; dy <= 1; ++dy) {
            int yy = py + dy; if ((unsigned)yy >= DS) continue;
            for (int dx = -1; dx <= 1; ++dx) {
                int xx = px + dx; if ((unsigned)xx >= DS) continue;
                msum += mask[(size_t)(2 * yy) * FH + 2 * xx];
            }
        }
        mmv[p] = (msum == 0.0f) ? 1.0f : 0.0f;
    }
}

// ---------- K2 (per batch): G[p][l] = sum_c b_ds[c,p] * f_ds[c,l] ----------
extern "C" __global__ __launch_bounds__(256) void k_ggemm(const float* __restrict__ bp,
                                                          const float* __restrict__ fp,
                                                          float* __restrict__ G) {
    int p0 = blockIdx.x * 64, l0 = blockIdx.y * 64;
    __shared__ float As[16][68];   // padded: conflict-free staging
    __shared__ float Bs[16][68];
    int tid = threadIdx.x;
    int tx = tid & 15, ty = tid >> 4;
    float acc[4][4] = {};
    int i0 = tid * 4, kk = i0 >> 6, pp = i0 & 63;
    for (int k0 = 0; k0 < NC; k0 += 16) {
        *(float4*)&As[kk][pp] = *(const float4*)(bp + (size_t)(k0 + kk) * NP + p0 + pp);
        *(float4*)&Bs[kk][pp] = *(const float4*)(fp + (size_t)(k0 + kk) * NP + l0 + pp);
        __syncthreads();
#pragma unroll
        for (int k = 0; k < 16; ++k) {
            float av[4], bv[4];
            *(float4*)av = *(float4*)&As[k][ty * 4];
            *(float4*)bv = *(float4*)&Bs[k][tx * 4];
#pragma unroll
            for (int i = 0; i < 4; ++i)
#pragma unroll
                for (int j = 0; j < 4; ++j) acc[i][j] += av[i] * bv[j];
        }
        __syncthreads();
    }
#pragma unroll
    for (int i = 0; i < 4; ++i) {
        float4 v = make_float4(acc[i][0], acc[i][1], acc[i][2], acc[i][3]);
        *(float4*)(G + (size_t)(p0 + ty * 4 + i) * NP + l0 + tx * 4) = v;
    }
}

// ---------- K3 (per batch): scores[p,l] = (sum_d G[p+d,l+d]) / norm[p], 4 l per thread ----------
extern "C" __global__ void k_scores(const float* __restrict__ G, const float* __restrict__ normv,
                                    float* __restrict__ sc) {
    int idx = blockIdx.x * 256 + threadIdx.x;     // 2304*576 = 1,327,104 exact
    int lq = idx % 576;
    int p  = idx / 576;
    int l0 = lq * 4;
    int py = p / DS, px = p % DS;
    int ly = l0 / DS, lx0 = l0 % DS;
    float a0 = 0.f, a1 = 0.f, a2 = 0.f, a3 = 0.f;
#pragma unroll
    for (int dy = -1; dy <= 1; ++dy) {
        int pyy = py + dy, lyy = ly + dy;
        if ((unsigned)pyy >= DS || (unsigned)lyy >= DS) continue;
#pragma unroll
        for (int dx = -1; dx <= 1; ++dx) {
            int pxx = px + dx;
            if ((unsigned)pxx >= DS) continue;
            const float* src = G + (size_t)(pyy * DS + pxx) * NP + (lyy * DS + lx0 + dx);
            F4u v = *(const F4u*)src;
            if ((unsigned)(lx0 + dx)     < DS) a0 += v.a;
            if ((unsigned)(lx0 + dx + 1) < DS) a1 += v.b;
            if ((unsigned)(lx0 + dx + 2) < DS) a2 += v.c;
            if ((unsigned)(lx0 + dx + 3) < DS) a3 += v.d;
        }
    }
    float ni = 1.0f / normv[p];
    *(float4*)(sc + (size_t)p * NP + l0) = make_float4(a0 * ni, a1 * ni, a2 * ni, a3 * ni);
}

// ---------- K4 (per batch): both fuse_diag passes, 4 l per thread ----------
extern "C" __global__ void k_fuse(const float* __restrict__ sc, float* __restrict__ sf) {
    int idx = blockIdx.x * 256 + threadIdx.x;     // 1,327,104 exact
    int lq = idx % 576;
    int p  = idx / 576;
    int l0 = lq * 4;
    int hb = p / DS, wb = p % DS;
    int hf = l0 / DS, wf0 = l0 % DS;
    float a0 = 0.f, a1 = 0.f, a2 = 0.f, a3 = 0.f;
#pragma unroll
    for (int e2 = -1; e2 <= 1; ++e2) {
        int qp = wb * DS + hb + e2;
        if ((unsigned)qp >= NP) continue;
        int wb2 = qp / DS, hb2 = qp % DS;
        int P1 = hb2 * DS + wb2;
        int he = hf + e2;
        int L1base;
        bool ev0, ev1, ev2, ev3;
        if ((unsigned)he < DS)  { L1base = he * DS + wf0; ev0 = ev1 = ev2 = ev3 = true; }
        else if (he == DS)      { L1base = wf0 + 1;
                                  ev0 = (wf0 + 1) < DS; ev1 = (wf0 + 2) < DS;
                                  ev2 = (wf0 + 3) < DS; ev3 = (wf0 + 4) < DS; }
        else /* he == -1 */     { L1base = 47 * DS + wf0 - 1;
                                  ev0 = wf0 >= 1; ev1 = ev2 = ev3 = true; }
#pragma unroll
        for (int e1 = -1; e1 <= 1; ++e1) {
            int Pz = P1 + e1;
            if ((unsigned)Pz >= NP) continue;
            int Lz = L1base + e1;
            const float* src = sc + (size_t)Pz * NP + Lz;
            F4u v = *(const F4u*)src;
            if (ev0 && (unsigned)(Lz)     < NP) a0 += v.a;
            if (ev1 && (unsigned)(Lz + 1) < NP) a1 += v.b;
            if (ev2 && (unsigned)(Lz + 2) < NP) a2 += v.c;
            if (ev3 && (unsigned)(Lz + 3) < NP) a3 += v.d;
        }
    }
    *(float4*)(sf + (size_t)p * NP + l0) = make_float4(a0, a1, a2, a3);
}

// ---------- K5a (per batch): per-column online softmax partials ----------
extern "C" __global__ void k_stats1(const float* __restrict__ sf, const float* __restrict__ mmv,
                                    float* __restrict__ pM, float* __restrict__ pS) {
    int l = blockIdx.x * 256 + threadIdx.x;
    int pst = blockIdx.y * 128;
    const float* base = sf + (size_t)pst * NP + l;
    float m = -1e30f, s = 0.f;
    for (int i = 0; i < 128; ++i) {
        float x = (mmv[pst + i] != 0.0f) ? 10.0f * base[(size_t)i * NP] : 0.0f;
        float mn = fmaxf(m, x);
        s = s * __expf(m - mn) + __expf(x - mn);
        m = mn;
    }
    int o = blockIdx.y * NP + l;
    pM[o] = m; pS[o] = s;
}

// ---------- K5b (per batch): combine -> M, 1/S ----------
extern "C" __global__ void k_stats2(const float* __restrict__ pM, const float* __restrict__ pS,
                                    float* __restrict__ M, float* __restrict__ Sinv) {
    int l = blockIdx.x * 256 + threadIdx.x;
    float m = -1e30f, s = 0.f;
    for (int j = 0; j < 18; ++j) {
        int o = j * NP + l;
        float mj = pM[o], sj = pS[o];
        float mn = fmaxf(m, mj);
        s = s * __expf(m - mn) + sj * __expf(mj - mn);
        m = mn;
    }
    M[l] = m;
    Sinv[l] = 1.0f / s;
}

// ---------- K6 (per batch): attn4[r, mt] ----------
extern "C" __global__ void k_attn4(const float* __restrict__ sf, const float* __restrict__ mmv,
                                   const float* __restrict__ M, const float* __restrict__ Sinv,
                                   float* __restrict__ a4) {
    long long idx = (long long)blockIdx.x * 256 + threadIdx.x;
    if (idx >= (long long)RR * RRP) return;
    int mt = (int)(idx % RRP);
    int r = (int)(idx / RRP);
    int ry = r / NR, rx = r % NR, my = mt / NR, mx = mt % NR;
    float acc = 0.f;
#pragma unroll
    for (int dy = 0; dy <= 1; ++dy) {
        int py = ry - dy, ly = my - dy;
        if ((unsigned)py >= DS || (unsigned)ly >= DS) continue;
#pragma unroll
        for (int dx = 0; dx <= 1; ++dx) {
            int px = rx - dx, lx = mx - dx;
            if ((unsigned)px >= DS || (unsigned)lx >= DS) continue;
            int p = py * DS + px, l = ly * DS + lx;
            if (mmv[p] != 0.0f)
                acc += __expf(10.0f * sf[(size_t)p * NP + l] - M[l]) * Sinv[l];
        }
    }
    a4[idx] = acc;
}

// ---------- K6b: Wpar[jb][par][c][r] = b[bb0+jb, c, 2ry-ay, 2rx-ax] (0-padded) ----------
extern "C" __global__ void k_wprep(const float* __restrict__ bfull, float* __restrict__ Wp, int bb0) {
    int idx = blockIdx.x * 256 + threadIdx.x;      // WPB = 2,490,368 exact (9728 blocks)
    int r = idx % RRP; int t = idx / RRP;
    int c = t % NC; t /= NC;
    int par = t & 3; int jb = t >> 2;
    int ay = par >> 1, ax = par & 1;
    float v = 0.f;
    if (r < RR) {
        int ry = r / NR, rx = r % NR;
        int by = 2 * ry - ay, bx = 2 * rx - ax;
        if ((unsigned)by < FH && (unsigned)bx < FH)
            v = bfull[(((size_t)(bb0 + jb) * NC + c) * FH + by) * FH + bx];
    }
    Wp[idx] = v;
}

// ---------- util: zero ----------
extern "C" __global__ void k_zero(float* __restrict__ p, int n) {
    int i = blockIdx.x * 256 + threadIdx.x;
    if (i < n) p[i] = 0.f;
}

// ---------- K7 (per pair): dbuf[jb][par][c][mt] += sum_{r in ks-chunk} Wp[c][r]*a4[r][mt] ----------
extern "C" __global__ __launch_bounds__(256) void k_deconv(const float* __restrict__ a4pair,
                                                           const float* __restrict__ Wp,
                                                           float* __restrict__ dbuf) {
    int m0 = blockIdx.x * 128;
    int z = blockIdx.z;                     // jb(2) x par(4) x ks(4)
    int ks = z & 3, par = (z >> 2) & 3, jb = z >> 4;
    const float* a4 = a4pair + (size_t)jb * A4B;
    const float* W  = Wp + (size_t)(jb * 4 + par) * NC * RRP;
    float* db       = dbuf + (size_t)(jb * 4 + par) * NC * RRP;

    __shared__ float As[16][132];   // [k][m 0..127], stride 132 -> all patterns <=2-way
    __shared__ float Ws[16][132];   // [k][c 0..127]
    int tid = threadIdx.x;
    int tx = tid & 15;              // m-group
    int ty = tid >> 4;              // c-group (0..15)
    int akk = tid >> 4;             // stage: k-row for As
    int amm = (tid & 15) * 8;       // stage: m-offset for As
    int wc  = tid & 127;            // stage: c for Ws
    int wk  = (tid >> 7) * 8;       // stage: k-offset for Ws

    float4 pa0, pa1, pw0, pw1;
    int kbase = ks * 608;

    float acc[8][8];
#pragma unroll
    for (int i = 0; i < 8; ++i)
#pragma unroll
        for (int j = 0; j < 8; ++j) acc[i][j] = 0.f;

    {   // first chunk load
        int rr = kbase + akk;
        if (rr < RR) {
            pa0 = *(const float4*)(a4 + (size_t)rr * RRP + m0 + amm);
            pa1 = *(const float4*)(a4 + (size_t)rr * RRP + m0 + amm + 4);
        } else { pa0 = make_float4(0, 0, 0, 0); pa1 = pa0; }
        pw0 = *(const float4*)(W + (size_t)wc * RRP + kbase + wk);
        pw1 = *(const float4*)(W + (size_t)wc * RRP + kbase + wk + 4);
    }

    for (int ch = 0; ch < 38; ++ch) {
        __syncthreads();
        *(float4*)&As[akk][amm]     = pa0;
        *(float4*)&As[akk][amm + 4] = pa1;
        Ws[wk + 0][wc] = pw0.x; Ws[wk + 1][wc] = pw0.y; Ws[wk + 2][wc] = pw0.z; Ws[wk + 3][wc] = pw0.w;
        Ws[wk + 4][wc] = pw1.x; Ws[wk + 5][wc] = pw1.y; Ws[wk + 6][wc] = pw1.z; Ws[wk + 7][wc] = pw1.w;
        __syncthreads();
        if (ch + 1 < 38) {
            int k0 = kbase + (ch + 1) * 16;
            int rr = k0 + akk;
            if (rr < RR) {
                pa0 = *(const float4*)(a4 + (size_t)rr * RRP + m0 + amm);
                pa1 = *(const float4*)(a4 + (size_t)rr * RRP + m0 + amm + 4);
            } else { pa0 = make_float4(0, 0, 0, 0); pa1 = pa0; }
            pw0 = *(const float4*)(W + (size_t)wc * RRP + k0 + wk);
            pw1 = *(const float4*)(W + (size_t)wc * RRP + k0 + wk + 4);
        }
#pragma unroll
        for (int k = 0; k < 16; ++k) {
            float av[8], bv[8];
            *(float4*)&av[0] = *(float4*)&As[k][tx * 4];
            *(float4*)&av[4] = *(float4*)&As[k][64 + tx * 4];
            *(float4*)&bv[0] = *(float4*)&Ws[k][ty * 4];
            *(float4*)&bv[4] = *(float4*)&Ws[k][64 + ty * 4];
#pragma unroll
            for (int i = 0; i < 8; ++i)
#pragma unroll
                for (int j = 0; j < 8; ++j) acc[i][j] += bv[i] * av[j];
        }
    }
#pragma unroll
    for (int i = 0; i < 8; ++i) {
        int c = (i < 4) ? (ty * 4 + i) : (64 + ty * 4 + i - 4);
        float* dr = db + (size_t)c * RRP + m0;
#pragma unroll
        for (int j = 0; j < 8; ++j) {
            int m = (j < 4) ? (tx * 4 + j) : (64 + tx * 4 + j - 4);
            atomicAdd(dr + m, acc[i][j]);
        }
    }
}

// ---------- K8 (per pair): out = 0.25 * dbuf[par(y,x)][c][mt(y,x)] ----------
extern "C" __global__ void k_finish(const float* __restrict__ dbuf, float* __restrict__ out, int bb0) {
    int idx = blockIdx.x * 256 + threadIdx.x;      // 2*128*96*96 = 2,359,296 exact (9216 blocks)
    int x = idx % FH; int t = idx / FH;
    int y = t % FH; t /= FH;
    int c = t % NC; int jb = t / NC;
    int ay = y & 1, oy = y >> 1, ax = x & 1, ox = x >> 1;
    int par = ay * 2 + ax;
    int mt = (oy + ay) * NR + (ox + ax);
    out[(((size_t)(bb0 + jb) * NC + c) * FH + y) * FH + x] =
        0.25f * dbuf[(((size_t)jb * 4 + par) * NC + c) * RRP + mt];
}

extern "C" void kernel_launch(void* const* d_in, const int* in_sizes, int n_in,
                              void* d_out, int out_size, void* d_ws, size_t ws_size,
                              hipStream_t stream) {
    const float* f = (const float*)d_in[0];
    const float* b = (const float*)d_in[1];
    const float* mask = (const float*)d_in[2];
    float* out = (float*)d_out;
    float* ws = (float*)d_ws;

    size_t o = 0;
    float* fds = ws + o;   o += (size_t)NB * NC * NP;   // 2,359,296
    float* bds = ws + o;   o += (size_t)NB * NC * NP;   // 2,359,296
    float* s2 = ws + o;    o += NB * DS * DS;           // 18,432
    float* normv = ws + o; o += NB * NP;                // 18,432
    float* mmv = ws + o;   o += NP;                     // 2,304
    float* Mst = ws + o;   o += NB * NP;                // 18,432
    float* Sinv = ws + o;  o += NB * NP;                // 18,432
    float* pM = ws + o;    o += (size_t)18 * NP;        // 41,472
    float* pS = ws + o;    o += (size_t)18 * NP;        // 41,472
    float* X = ws + o;     o += (size_t)PP;             // 5,308,416  (G / sf / Wpar)
    float* Y = ws + o;     o += (size_t)PP;             // 5,308,416  (scores / dbuf)
    float* Z = ws + o;     o += (size_t)2 * A4B;        // 11,678,464 (attn4 pair)
    // total = 27,172,864 floats = 108.7 MB (identical to proven layout)

    if (ws_size < o * sizeof(float)) return;

    hipLaunchKernelGGL(k_prep, dim3(9216), dim3(256), 0, stream, f, b, fds, bds);
    hipLaunchKernelGGL(k_s2,   dim3(72),   dim3(256), 0, stream, bds, s2);
    hipLaunchKernelGGL(k_norm, dim3(72),   dim3(256), 0, stream, s2, mask, normv, mmv);

    for (int pair = 0; pair < 4; ++pair) {
        for (int j = 0; j < 2; ++j) {
            int bb = pair * 2 + j;
            const float* bp = bds + (size_t)bb * NC * NP;
            const float* fp = fds + (size_t)bb * NC * NP;
            hipLaunchKernelGGL(k_ggemm,  dim3(36, 36), dim3(256), 0, stream, bp, fp, X);
            hipLaunchKernelGGL(k_scores, dim3(5184),   dim3(256), 0, stream, X, normv + (size_t)bb * NP, Y);
            hipLaunchKernelGGL(k_fuse,   dim3(5184),   dim3(256), 0, stream, Y, X);
            hipLaunchKernelGGL(k_stats1, dim3(9, 18),  dim3(256), 0, stream, X, mmv, pM, pS);
            hipLaunchKernelGGL(k_stats2, dim3(9),      dim3(256), 0, stream, pM, pS,
                               Mst + (size_t)bb * NP, Sinv + (size_t)bb * NP);
            hipLaunchKernelGGL(k_attn4,  dim3(22810),  dim3(256), 0, stream, X, mmv,
                               Mst + (size_t)bb * NP, Sinv + (size_t)bb * NP, Z + (size_t)j * A4B);
        }
        // X is free now (sf consumed); reuse as Wpar. Y free; reuse as dbuf.
        hipLaunchKernelGGL(k_wprep,  dim3(9728),       dim3(256), 0, stream, b, X, pair * 2);
        hipLaunchKernelGGL(k_zero,   dim3(9728),       dim3(256), 0, stream, Y, (int)DBB);
        hipLaunchKernelGGL(k_deconv, dim3(19, 1, 32),  dim3(256), 0, stream, Z, X, Y);
        hipLaunchKernelGGL(k_finish, dim3(9216),       dim3(256), 0, stream, Y, out, pair * 2);
    }
}

// Round 6
// 1661.953 us; speedup vs baseline: 1.6100x; 1.4992x over previous
//
#include <hip/hip_runtime.h>

#define NB 8
#define NC 128
#define FH 96
#define DS 48
#define NP 2304                 // 48*48 patches / locations
#define PP 5308416LL            // NP*NP (per batch)
#define NR 49
#define RR 2401                 // 49*49
#define RRP 2432                // padded attn4 col count (19*128)
#define A4B 5839232LL           // RR*RRP per batch
#define WPB 2490368             // 2*4*NC*RRP  (pair Wpar bf16 elems) = 9728 blocks
#define DSL 2490368LL           // dbuf K-slice stride in floats (8*NC*RRP)

typedef unsigned short u16;
typedef __attribute__((ext_vector_type(8))) short bf16x8;
typedef __attribute__((ext_vector_type(4))) float f32x4;

struct F4u { float a, b, c, d; };   // 4-byte-aligned 4-float load

__device__ __forceinline__ u16 f2bf(float f) {   // fp32 -> bf16 RNE
    unsigned u = __float_as_uint(f);
    return (u16)((u + 0x7FFFu + ((u >> 16) & 1u)) >> 16);
}

// ---------- K1a: downsample f,b by 2 (all batches) ----------
extern "C" __global__ void k_prep(const float* __restrict__ f, const float* __restrict__ b,
                                  float* __restrict__ fds, float* __restrict__ bds) {
    int idx = blockIdx.x * 256 + threadIdx.x;
    if (idx >= NB * NC * DS * DS) return;
    int x = idx % DS; int r = idx / DS; int y = r % DS; int bc = r / DS;
    size_t src = ((size_t)bc * FH + 2 * y) * FH + 2 * x;
    fds[idx] = f[src];
    bds[idx] = b[src];
}

// ---------- K1b: S2[b,y,x] = sum_c b_ds^2 ----------
extern "C" __global__ void k_s2(const float* __restrict__ bds, float* __restrict__ s2) {
    int idx = blockIdx.x * 256 + threadIdx.x;
    if (idx >= NB * DS * DS) return;
    int sp = idx % (DS * DS); int bb = idx / (DS * DS);
    const float* p = bds + (size_t)bb * NC * DS * DS + sp;
    float acc = 0.f;
    for (int c = 0; c < NC; ++c) { float v = p[(size_t)c * DS * DS]; acc += v * v; }
    s2[idx] = acc;
}

// ---------- K1c: norm, mm ----------
extern "C" __global__ void k_norm(const float* __restrict__ s2, const float* __restrict__ mask,
                                  float* __restrict__ normv, float* __restrict__ mmv) {
    int idx = blockIdx.x * 256 + threadIdx.x;
    if (idx >= NB * NP) return;
    int p = idx % NP; int bb = idx / NP;
    int py = p / DS, px = p % DS;
    const float* s2b = s2 + bb * DS * DS;
    float acc = 0.f;
    for (int dy = -1; dy <= 1; ++dy) {
        int yy = py + dy; if ((unsigned)yy >= DS) continue;
        for (int dx = -1; dx <= 1; ++dx) {
            int xx = px + dx; if ((unsigned)xx >= DS) continue;
            acc += s2b[yy * DS + xx];
        }
    }
    normv[idx] = sqrtf(acc + 1152.0f * 1e-4f);
    if (bb == 0) {
        float msum = 0.f;
        for (int dy = -1; dy <= 1; ++dy) {
            int yy = py + dy; if ((unsigned)yy >= DS) continue;
            for (int dx = -1; dx <= 1; ++dx) {
                int xx = px + dx; if ((unsigned)xx >= DS) continue;
                msum += mask[(size_t)(2 * yy) * FH + 2 * xx];
            }
        }
        mmv[p] = (msum == 0.0f) ? 1.0f : 0.0f;
    }
}

// ---------- K2 (per batch): G[p][l] = sum_c b_ds[c,p] * f_ds[c,l] ----------
extern "C" __global__ __launch_bounds__(256) void k_ggemm(const float* __restrict__ bp,
                                                          const float* __restrict__ fp,
                                                          float* __restrict__ G) {
    int p0 = blockIdx.x * 64, l0 = blockIdx.y * 64;
    __shared__ float As[16][68];
    __shared__ float Bs[16][68];
    int tid = threadIdx.x;
    int tx = tid & 15, ty = tid >> 4;
    float acc[4][4] = {};
    int i0 = tid * 4, kk = i0 >> 6, pp = i0 & 63;
    for (int k0 = 0; k0 < NC; k0 += 16) {
        *(float4*)&As[kk][pp] = *(const float4*)(bp + (size_t)(k0 + kk) * NP + p0 + pp);
        *(float4*)&Bs[kk][pp] = *(const float4*)(fp + (size_t)(k0 + kk) * NP + l0 + pp);
        __syncthreads();
#pragma unroll
        for (int k = 0; k < 16; ++k) {
            float av[4], bv[4];
            *(float4*)av = *(float4*)&As[k][ty * 4];
            *(float4*)bv = *(float4*)&Bs[k][tx * 4];
#pragma unroll
            for (int i = 0; i < 4; ++i)
#pragma unroll
                for (int j = 0; j < 4; ++j) acc[i][j] += av[i] * bv[j];
        }
        __syncthreads();
    }
#pragma unroll
    for (int i = 0; i < 4; ++i) {
        float4 v = make_float4(acc[i][0], acc[i][1], acc[i][2], acc[i][3]);
        *(float4*)(G + (size_t)(p0 + ty * 4 + i) * NP + l0 + tx * 4) = v;
    }
}

// ---------- K3 (per batch): scores[p,l] = (sum_d G[p+d,l+d]) / norm[p], 4 l per thread ----------
extern "C" __global__ void k_scores(const float* __restrict__ G, const float* __restrict__ normv,
                                    float* __restrict__ sc) {
    int idx = blockIdx.x * 256 + threadIdx.x;     // 2304*576 exact
    int lq = idx % 576;
    int p  = idx / 576;
    int l0 = lq * 4;
    int py = p / DS, px = p % DS;
    int ly = l0 / DS, lx0 = l0 % DS;
    float a0 = 0.f, a1 = 0.f, a2 = 0.f, a3 = 0.f;
#pragma unroll
    for (int dy = -1; dy <= 1; ++dy) {
        int pyy = py + dy, lyy = ly + dy;
        if ((unsigned)pyy >= DS || (unsigned)lyy >= DS) continue;
#pragma unroll
        for (int dx = -1; dx <= 1; ++dx) {
            int pxx = px + dx;
            if ((unsigned)pxx >= DS) continue;
            const float* src = G + (size_t)(pyy * DS + pxx) * NP + (lyy * DS + lx0 + dx);
            F4u v = *(const F4u*)src;
            if ((unsigned)(lx0 + dx)     < DS) a0 += v.a;
            if ((unsigned)(lx0 + dx + 1) < DS) a1 += v.b;
            if ((unsigned)(lx0 + dx + 2) < DS) a2 += v.c;
            if ((unsigned)(lx0 + dx + 3) < DS) a3 += v.d;
        }
    }
    float ni = 1.0f / normv[p];
    *(float4*)(sc + (size_t)p * NP + l0) = make_float4(a0 * ni, a1 * ni, a2 * ni, a3 * ni);
}

// ---------- K4 (per batch): both fuse_diag passes, 4 l per thread ----------
extern "C" __global__ void k_fuse(const float* __restrict__ sc, float* __restrict__ sf) {
    int idx = blockIdx.x * 256 + threadIdx.x;     // 1,327,104 exact
    int lq = idx % 576;
    int p  = idx / 576;
    int l0 = lq * 4;
    int hb = p / DS, wb = p % DS;
    int hf = l0 / DS, wf0 = l0 % DS;
    float a0 = 0.f, a1 = 0.f, a2 = 0.f, a3 = 0.f;
#pragma unroll
    for (int e2 = -1; e2 <= 1; ++e2) {
        int qp = wb * DS + hb + e2;
        if ((unsigned)qp >= NP) continue;
        int wb2 = qp / DS, hb2 = qp % DS;
        int P1 = hb2 * DS + wb2;
        int he = hf + e2;
        int L1base;
        bool ev0, ev1, ev2, ev3;
        if ((unsigned)he < DS)  { L1base = he * DS + wf0; ev0 = ev1 = ev2 = ev3 = true; }
        else if (he == DS)      { L1base = wf0 + 1;
                                  ev0 = (wf0 + 1) < DS; ev1 = (wf0 + 2) < DS;
                                  ev2 = (wf0 + 3) < DS; ev3 = (wf0 + 4) < DS; }
        else /* he == -1 */     { L1base = 47 * DS + wf0 - 1;
                                  ev0 = wf0 >= 1; ev1 = ev2 = ev3 = true; }
#pragma unroll
        for (int e1 = -1; e1 <= 1; ++e1) {
            int Pz = P1 + e1;
            if ((unsigned)Pz >= NP) continue;
            int Lz = L1base + e1;
            const float* src = sc + (size_t)Pz * NP + Lz;
            F4u v = *(const F4u*)src;
            if (ev0 && (unsigned)(Lz)     < NP) a0 += v.a;
            if (ev1 && (unsigned)(Lz + 1) < NP) a1 += v.b;
            if (ev2 && (unsigned)(Lz + 2) < NP) a2 += v.c;
            if (ev3 && (unsigned)(Lz + 3) < NP) a3 += v.d;
        }
    }
    *(float4*)(sf + (size_t)p * NP + l0) = make_float4(a0, a1, a2, a3);
}

// ---------- K5a (per batch): per-column online softmax partials ----------
extern "C" __global__ void k_stats1(const float* __restrict__ sf, const float* __restrict__ mmv,
                                    float* __restrict__ pM, float* __restrict__ pS) {
    int l = blockIdx.x * 256 + threadIdx.x;
    int pst = blockIdx.y * 128;
    const float* base = sf + (size_t)pst * NP + l;
    float m = -1e30f, s = 0.f;
    for (int i = 0; i < 128; ++i) {
        float x = (mmv[pst + i] != 0.0f) ? 10.0f * base[(size_t)i * NP] : 0.0f;
        float mn = fmaxf(m, x);
        s = s * __expf(m - mn) + __expf(x - mn);
        m = mn;
    }
    int o = blockIdx.y * NP + l;
    pM[o] = m; pS[o] = s;
}

// ---------- K5b (per batch): combine -> M, 1/S ----------
extern "C" __global__ void k_stats2(const float* __restrict__ pM, const float* __restrict__ pS,
                                    float* __restrict__ M, float* __restrict__ Sinv) {
    int l = blockIdx.x * 256 + threadIdx.x;
    float m = -1e30f, s = 0.f;
    for (int j = 0; j < 18; ++j) {
        int o = j * NP + l;
        float mj = pM[o], sj = pS[o];
        float mn = fmaxf(m, mj);
        s = s * __expf(m - mn) + sj * __expf(mj - mn);
        m = mn;
    }
    M[l] = m;
    Sinv[l] = 1.0f / s;
}

// ---------- K6 (per batch): attn4[r, mt] (fp32, row-major r) ----------
extern "C" __global__ void k_attn4(const float* __restrict__ sf, const float* __restrict__ mmv,
                                   const float* __restrict__ M, const float* __restrict__ Sinv,
                                   float* __restrict__ a4) {
    long long idx = (long long)blockIdx.x * 256 + threadIdx.x;
    if (idx >= (long long)RR * RRP) return;
    int mt = (int)(idx % RRP);
    int r = (int)(idx / RRP);
    int ry = r / NR, rx = r % NR, my = mt / NR, mx = mt % NR;
    float acc = 0.f;
#pragma unroll
    for (int dy = 0; dy <= 1; ++dy) {
        int py = ry - dy, ly = my - dy;
        if ((unsigned)py >= DS || (unsigned)ly >= DS) continue;
#pragma unroll
        for (int dx = 0; dx <= 1; ++dx) {
            int px = rx - dx, lx = mx - dx;
            if ((unsigned)px >= DS || (unsigned)lx >= DS) continue;
            int p = py * DS + px, l = ly * DS + lx;
            if (mmv[p] != 0.0f)
                acc += __expf(10.0f * sf[(size_t)p * NP + l] - M[l]) * Sinv[l];
        }
    }
    a4[idx] = acc;
}

// ---------- K6b: Wpar[jb][par][c][r] = bf16(b[bb0+jb, c, 2ry-ay, 2rx-ax]) (0-padded) ----------
extern "C" __global__ void k_wprep(const float* __restrict__ bfull, u16* __restrict__ Wp, int bb0) {
    int idx = blockIdx.x * 256 + threadIdx.x;      // WPB exact (9728 blocks)
    int r = idx % RRP; int t = idx / RRP;
    int c = t % NC; t /= NC;
    int par = t & 3; int jb = t >> 2;
    int ay = par >> 1, ax = par & 1;
    float v = 0.f;
    if (r < RR) {
        int ry = r / NR, rx = r % NR;
        int by = 2 * ry - ay, bx = 2 * rx - ax;
        if ((unsigned)by < FH && (unsigned)bx < FH)
            v = bfull[(((size_t)(bb0 + jb) * NC + c) * FH + by) * FH + bx];
    }
    Wp[idx] = f2bf(v);
}

// ---------- K7 (per pair): MFMA GEMM  dbuf[ks][jbpar][c][mt] = sum_{r in ks-half} W[c,r]*a4[r,mt]
// A = W (bf16, [c][r] row-major, direct global frag loads)
// B = a4 (fp32 in Z) staged per 32-r step into transposed LDS [mt][r] bf16, stride 36
extern "C" __global__ __launch_bounds__(256) void k_deconv(const float* __restrict__ a4pair,
                                                           const u16* __restrict__ Wp,
                                                           float* __restrict__ dbuf) {
    const int m0 = blockIdx.x * 128;
    const int ks = blockIdx.y;                 // K half: r in [ks*1216, ks*1216+1216)
    const int jbpar = blockIdx.z;              // jb*4 + par
    const float* a4 = a4pair + (size_t)(jbpar >> 2) * A4B;
    const u16* W = Wp + (size_t)jbpar * NC * RRP;
    float* db = dbuf + ((size_t)ks * 8 + jbpar) * NC * RRP;

    __shared__ u16 a4T[128][36];               // [mt_local][r_local], stride 36 (2-way reads)

    const int tid = threadIdx.x;
    const int lane = tid & 63;
    const int w = tid >> 6;                    // wave 0..3
    const int wc = w >> 1, wm = w & 1;         // 2c x 2m wave grid
    const int c0w = wc * 64;
    const int lr = lane >> 4;                  // k-group 0..3
    const int ln = lane & 15;

    const int mtl = tid & 127;                 // stager: mt column
    const int rg = tid >> 7;                   // stager: r half (0/1)
    const int ksbase = ks * 1216;
    const float* a4col = a4 + (size_t)(m0 + mtl);

    f32x4 acc[4][4];
#pragma unroll
    for (int i = 0; i < 4; ++i)
#pragma unroll
        for (int j = 0; j < 4; ++j) acc[i][j] = {0.f, 0.f, 0.f, 0.f};

    float cur[16], nxt[16];
#pragma unroll
    for (int i = 0; i < 16; ++i) nxt[i] = 0.f;
    {
        int rb = ksbase + rg * 16;
#pragma unroll
        for (int i = 0; i < 16; ++i) { int r = rb + i; cur[i] = (r < RR) ? a4col[(size_t)r * RRP] : 0.f; }
    }

    for (int s = 0; s < 38; ++s) {
        __syncthreads();                       // LDS free (prev compute done)
        {
            u16* dst = &a4T[mtl][rg * 16];
#pragma unroll
            for (int q = 0; q < 4; ++q) {
                ushort4 w4 = make_ushort4(f2bf(cur[4 * q]), f2bf(cur[4 * q + 1]),
                                          f2bf(cur[4 * q + 2]), f2bf(cur[4 * q + 3]));
                *(ushort4*)(dst + 4 * q) = w4;
            }
        }
        __syncthreads();
        if (s + 1 < 38) {                      // issue next tile loads early (hide under MFMA)
            int rb = ksbase + (s + 1) * 32 + rg * 16;
#pragma unroll
            for (int i = 0; i < 16; ++i) { int r = rb + i; nxt[i] = (r < RR) ? a4col[(size_t)r * RRP] : 0.f; }
        }
        const int r0 = ksbase + s * 32;
        bf16x8 af[4], bfr[4];
#pragma unroll
        for (int cf = 0; cf < 4; ++cf) {       // A-frag: 16B contiguous global (L2-resident W)
            const u16* ap = W + (size_t)(c0w + cf * 16 + ln) * RRP + r0 + lr * 8;
            af[cf] = *(const bf16x8*)ap;
        }
#pragma unroll
        for (int mf = 0; mf < 4; ++mf) {       // B-frag: 2x ds_read_b64 from transposed tile
            const u16* bp = &a4T[wm * 64 + mf * 16 + ln][lr * 8];
            union { ushort4 h[2]; bf16x8 v; } tmp;
            tmp.h[0] = *(const ushort4*)bp;
            tmp.h[1] = *(const ushort4*)(bp + 4);
            bfr[mf] = tmp.v;
        }
#pragma unroll
        for (int cf = 0; cf < 4; ++cf)
#pragma unroll
            for (int mf = 0; mf < 4; ++mf)
                acc[cf][mf] = __builtin_amdgcn_mfma_f32_16x16x32_bf16(af[cf], bfr[mf], acc[cf][mf], 0, 0, 0);
#pragma unroll
        for (int i = 0; i < 16; ++i) cur[i] = nxt[i];
    }

    // epilogue: C/D frag layout col=lane&15, row=(lane>>4)*4+reg
#pragma unroll
    for (int cf = 0; cf < 4; ++cf) {
#pragma unroll
        for (int mf = 0; mf < 4; ++mf) {
            size_t base = (size_t)(c0w + cf * 16 + lr * 4) * RRP + (size_t)(m0 + wm * 64 + mf * 16 + ln);
#pragma unroll
            for (int q = 0; q < 4; ++q)
                db[base + (size_t)q * RRP] = acc[cf][mf][q];
        }
    }
}

// ---------- K8 (per pair): out = 0.25 * (dbuf_ks0 + dbuf_ks1) with parity gather ----------
extern "C" __global__ void k_finish(const float* __restrict__ dbuf, float* __restrict__ out, int bb0) {
    int idx = blockIdx.x * 256 + threadIdx.x;      // 2*128*96*96 exact (9216 blocks)
    int x = idx % FH; int t = idx / FH;
    int y = t % FH; t /= FH;
    int c = t % NC; int jb = t / NC;
    int ay = y & 1, oy = y >> 1, ax = x & 1, ox = x >> 1;
    int par = ay * 2 + ax;
    int mt = (oy + ay) * NR + (ox + ax);
    size_t o0 = (((size_t)jb * 4 + par) * NC + c) * RRP + mt;
    out[(((size_t)(bb0 + jb) * NC + c) * FH + y) * FH + x] =
        0.25f * (dbuf[o0] + dbuf[o0 + DSL]);
}

extern "C" void kernel_launch(void* const* d_in, const int* in_sizes, int n_in,
                              void* d_out, int out_size, void* d_ws, size_t ws_size,
                              hipStream_t stream) {
    const float* f = (const float*)d_in[0];
    const float* b = (const float*)d_in[1];
    const float* mask = (const float*)d_in[2];
    float* out = (float*)d_out;
    float* ws = (float*)d_ws;

    size_t o = 0;
    float* fds = ws + o;   o += (size_t)NB * NC * NP;   // 2,359,296
    float* bds = ws + o;   o += (size_t)NB * NC * NP;   // 2,359,296
    float* s2 = ws + o;    o += NB * DS * DS;           // 18,432
    float* normv = ws + o; o += NB * NP;                // 18,432
    float* mmv = ws + o;   o += NP;                     // 2,304
    float* Mst = ws + o;   o += NB * NP;                // 18,432
    float* Sinv = ws + o;  o += NB * NP;                // 18,432
    float* pM = ws + o;    o += (size_t)18 * NP;        // 41,472
    float* pS = ws + o;    o += (size_t)18 * NP;        // 41,472
    float* X = ws + o;     o += (size_t)PP;             // 5,308,416  (G / sf / Wpar-bf16)
    float* Y = ws + o;     o += (size_t)PP;             // 5,308,416  (scores / dbuf 2 K-slices)
    float* Z = ws + o;     o += (size_t)2 * A4B;        // 11,678,464 (attn4 pair, fp32)
    // total = 27,172,864 floats = 108.7 MB (identical to proven layout)

    if (ws_size < o * sizeof(float)) return;

    hipLaunchKernelGGL(k_prep, dim3(9216), dim3(256), 0, stream, f, b, fds, bds);
    hipLaunchKernelGGL(k_s2,   dim3(72),   dim3(256), 0, stream, bds, s2);
    hipLaunchKernelGGL(k_norm, dim3(72),   dim3(256), 0, stream, s2, mask, normv, mmv);

    for (int pair = 0; pair < 4; ++pair) {
        for (int j = 0; j < 2; ++j) {
            int bb = pair * 2 + j;
            const float* bp = bds + (size_t)bb * NC * NP;
            const float* fp = fds + (size_t)bb * NC * NP;
            hipLaunchKernelGGL(k_ggemm,  dim3(36, 36), dim3(256), 0, stream, bp, fp, X);
            hipLaunchKernelGGL(k_scores, dim3(5184),   dim3(256), 0, stream, X, normv + (size_t)bb * NP, Y);
            hipLaunchKernelGGL(k_fuse,   dim3(5184),   dim3(256), 0, stream, Y, X);
            hipLaunchKernelGGL(k_stats1, dim3(9, 18),  dim3(256), 0, stream, X, mmv, pM, pS);
            hipLaunchKernelGGL(k_stats2, dim3(9),      dim3(256), 0, stream, pM, pS,
                               Mst + (size_t)bb * NP, Sinv + (size_t)bb * NP);
            hipLaunchKernelGGL(k_attn4,  dim3(22810),  dim3(256), 0, stream, X, mmv,
                               Mst + (size_t)bb * NP, Sinv + (size_t)bb * NP, Z + (size_t)j * A4B);
        }
        // X free (sf consumed) -> Wpar bf16; Y free (scores consumed) -> dbuf (2 K-slices)
        hipLaunchKernelGGL(k_wprep,  dim3(9728),      dim3(256), 0, stream, b, (u16*)X, pair * 2);
        hipLaunchKernelGGL(k_deconv, dim3(19, 2, 8),  dim3(256), 0, stream, Z, (const u16*)X, Y);
        hipLaunchKernelGGL(k_finish, dim3(9216),      dim3(256), 0, stream, Y, out, pair * 2);
    }
}